// Round 3
// baseline (399.132 us; speedup 1.0000x reference)
//
#include <hip/hip_runtime.h>
#include <math.h>

// Problem constants (from reference setup_inputs)
#define BATCH 512
#define LEN   16384
#define WIN   5
#define WOUT  (LEN - WIN + 1)   // 16380
#define NW    16                 // windows per thread (register sliding window)
#define RUNS  ((WOUT + NW - 1) / NW)   // 1024 runs per row
#define NELEM (NW + WIN - 1)     // 20 elements loaded per (thread, batch)
#define NCHUNK 128               // batch chunks
#define BPER  (BATCH / NCHUNK)   // 4 batches per thread
#define TPB   256

__device__ __forceinline__ float sigmoid_p(float p0, float p1) {
    // softmax over 2 classes, class 1
    return 1.0f / (1.0f + __expf(p0 - p1));
}

// Kernel 1: thread = (run of NW windows, batch chunk). Loads 20 consecutive
// elements per batch with int4/float4, computes sigmoid once per element,
// produces NW window sums via register sliding updates. Accumulates d^2 and
// msum per window over its BPER batches, then atomically adds into global
// per-window accumulators.
__global__ void bcl_main_kernel(const float* __restrict__ pred,
                                const int*   __restrict__ tgt,
                                const int*   __restrict__ msk,
                                float* __restrict__ acc_d2,
                                float* __restrict__ acc_ms) {
    const int run = blockIdx.x * TPB + threadIdx.x;       // 0..RUNS-1 (grid exact)
    const int e0  = min(run * NW, LEN - NELEM);           // clamp tail (run 1023)
    const int b0  = blockIdx.y * BPER;

    float accd2[NW], accms[NW];
#pragma unroll
    for (int w = 0; w < NW; ++w) { accd2[w] = 0.f; accms[w] = 0.f; }

    for (int b = b0; b < b0 + BPER; ++b) {
        const size_t rowoff = (size_t)b * LEN + e0;
        const int4*   mv = (const int4*)(msk + rowoff);
        const int4*   tv = (const int4*)(tgt + rowoff);
        const float4* pv = (const float4*)(pred + rowoff * 2);

        float m[NELEM], tm[NELEM], pm[NELEM], p2m[NELEM];
#pragma unroll
        for (int q = 0; q < NELEM / 4; ++q) {
            const int4 mm = mv[q];
            const int4 tt = tv[q];
            m[4*q+0] = (float)mm.x;  tm[4*q+0] = (float)(tt.x & mm.x);
            m[4*q+1] = (float)mm.y;  tm[4*q+1] = (float)(tt.y & mm.y);
            m[4*q+2] = (float)mm.z;  tm[4*q+2] = (float)(tt.z & mm.z);
            m[4*q+3] = (float)mm.w;  tm[4*q+3] = (float)(tt.w & mm.w);
        }
#pragma unroll
        for (int q = 0; q < NELEM / 2; ++q) {
            const float4 pp = pv[q];                       // (p0,p1, p0,p1)
            const float pa = sigmoid_p(pp.x, pp.y);
            const float pb = sigmoid_p(pp.z, pp.w);
            pm [2*q+0] = pa * m[2*q+0];
            p2m[2*q+0] = pa * pa * m[2*q+0];
            pm [2*q+1] = pb * m[2*q+1];
            p2m[2*q+1] = pb * pb * m[2*q+1];
        }

        // initial window (elements 0..4)
        float sm  = m[0]  + m[1]  + m[2]  + m[3]  + m[4];
        float stm = tm[0] + tm[1] + tm[2] + tm[3] + tm[4];
        float spm = pm[0] + pm[1] + pm[2] + pm[3] + pm[4];
        float sp2 = p2m[0]+ p2m[1]+ p2m[2]+ p2m[3]+ p2m[4];

#pragma unroll
        for (int w = 0; w < NW; ++w) {
            // st2m == stm since t in {0,1}
            const float denom = fmaxf(sm, 1.0f);
            const float inv   = 1.0f / denom;
            const float pmean = spm * inv;
            const float tmean = stm * inv;
            const float pvar  = (sp2 - 2.0f * pmean * spm + pmean * pmean * sm) * inv;
            const float tvar  = (stm - 2.0f * tmean * stm + tmean * tmean * sm) * inv;
            const float d = pvar - tvar;
            accd2[w] += d * d;
            accms[w] += sm;
            if (w < NW - 1) {   // slide
                sm  += m[w + WIN]   - m[w];
                stm += tm[w + WIN]  - tm[w];
                spm += pm[w + WIN]  - pm[w];
                sp2 += p2m[w + WIN] - p2m[w];
            }
        }
    }

    const int jfirst = run * NW;   // windows below this belong to previous run
#pragma unroll
    for (int w = 0; w < NW; ++w) {
        const int j = e0 + w;
        if (j >= jfirst) {         // only false for the clamped tail run
            atomicAdd(&acc_d2[j], accd2[w]);
            atomicAdd(&acc_ms[j], accms[w]);
        }
    }
}

// Kernel 2: finalize — per-window valid/mse from accumulators, block-reduce
// in double, atomic accumulate, last block writes the scalar.
__global__ void bcl_finalize(const float* __restrict__ acc_d2,
                             const float* __restrict__ acc_ms,
                             double* __restrict__ accum,   // [num, cnt]
                             unsigned int* __restrict__ ticket,
                             float* __restrict__ out) {
    const int j = blockIdx.x * blockDim.x + threadIdx.x;
    double num = 0.0, cnt = 0.0;
    if (j < WOUT) {
        const float d2 = acc_d2[j];
        const float ms = acc_ms[j];
        if (ms > 0.f) {
            num = (double)d2 * (1.0 / (double)BATCH);
            cnt = 1.0;
        }
    }
    for (int off = 32; off > 0; off >>= 1) {
        num += __shfl_down(num, off, 64);
        cnt += __shfl_down(cnt, off, 64);
    }
    __shared__ double s_num[4], s_cnt[4];
    const int lane = threadIdx.x & 63, wave = threadIdx.x >> 6;
    if (lane == 0) { s_num[wave] = num; s_cnt[wave] = cnt; }
    __syncthreads();
    if (threadIdx.x == 0) {
        double n = 0.0, c = 0.0;
        const int nw = (int)(blockDim.x >> 6);
        for (int wv = 0; wv < nw; ++wv) { n += s_num[wv]; c += s_cnt[wv]; }
        atomicAdd(&accum[0], n);
        atomicAdd(&accum[1], c);
        __threadfence();
        const unsigned int t = atomicAdd(ticket, 1u);
        if (t == gridDim.x - 1) {
            out[0] = (float)(accum[0] / fmax(accum[1], 1.0));
        }
    }
}

extern "C" void kernel_launch(void* const* d_in, const int* in_sizes, int n_in,
                              void* d_out, int out_size, void* d_ws, size_t ws_size,
                              hipStream_t stream) {
    const float* pred = (const float*)d_in[0];
    const int*   tgt  = (const int*)d_in[1];
    const int*   msk  = (const int*)d_in[2];
    float* out = (float*)d_out;

    // Workspace layout: acc_d2[WOUT], acc_ms[WOUT], (align16) accum[2] dbl, ticket
    float* acc_d2 = (float*)d_ws;
    float* acc_ms = acc_d2 + WOUT;
    size_t off = ((size_t)WOUT * 2 * sizeof(float) + 15) & ~(size_t)15;
    double* accum = (double*)((char*)d_ws + off);
    unsigned int* ticket = (unsigned int*)(accum + 2);
    const size_t zbytes = off + 2 * sizeof(double) + sizeof(unsigned int);

    // ws is re-poisoned to 0xAA before every call — zero what we use (~131 KB)
    hipMemsetAsync(d_ws, 0, zbytes, stream);

    dim3 g1(RUNS / TPB, NCHUNK);   // (4, 128) = 512 blocks
    bcl_main_kernel<<<g1, TPB, 0, stream>>>(pred, tgt, msk, acc_d2, acc_ms);

    const int FBLKS = (WOUT + TPB - 1) / TPB;  // 64
    bcl_finalize<<<FBLKS, TPB, 0, stream>>>(acc_d2, acc_ms, accum, ticket, out);
}

// Round 4
// 234.135 us; speedup vs baseline: 1.7047x; 1.7047x over previous
//
#include <hip/hip_runtime.h>
#include <math.h>

// Problem constants (from reference setup_inputs)
#define BATCH 512
#define LEN   16384
#define WIN   5
#define WOUT  (LEN - WIN + 1)   // 16380
#define NW    16                 // windows per thread (register sliding window)
#define RUNS  ((WOUT + NW - 1) / NW)   // 1024 runs per row
#define NELEM (NW + WIN - 1)     // 20 elements loaded per (thread, batch)
#define TPB   256

__device__ __forceinline__ float sigmoid_p(float p0, float p1) {
    // softmax over 2 classes, class 1
    return 1.0f / (1.0f + __expf(p0 - p1));
}

// Kernel 1: thread = (run of NW windows, batch chunk blockIdx.y). Loads 20
// consecutive elements per batch with int4/float4, computes sigmoid once per
// element, produces NW window sums via register sliding updates. Accumulates
// d^2 and msum per window over its bper batches, then writes CONTENTION-FREE
// per-chunk partials (coalesced stores — round 3's atomics cost 250 us in
// cacheline ping-pong; never again).
__global__ void bcl_main_kernel(const float* __restrict__ pred,
                                const int*   __restrict__ tgt,
                                const int*   __restrict__ msk,
                                float* __restrict__ part_d2,
                                float* __restrict__ part_ms,
                                int bper) {
    const int run = blockIdx.x * TPB + threadIdx.x;       // 0..RUNS-1 (grid exact)
    const int e0  = min(run * NW, LEN - NELEM);           // clamp tail (run 1023)
    const int b0  = blockIdx.y * bper;

    float accd2[NW], accms[NW];
#pragma unroll
    for (int w = 0; w < NW; ++w) { accd2[w] = 0.f; accms[w] = 0.f; }

    for (int b = b0; b < b0 + bper; ++b) {
        const size_t rowoff = (size_t)b * LEN + e0;
        const int4*   mv = (const int4*)(msk + rowoff);
        const int4*   tv = (const int4*)(tgt + rowoff);
        const float4* pv = (const float4*)(pred + rowoff * 2);

        float m[NELEM], tm[NELEM], pm[NELEM], p2m[NELEM];
#pragma unroll
        for (int q = 0; q < NELEM / 4; ++q) {
            const int4 mm = mv[q];
            const int4 tt = tv[q];
            m[4*q+0] = (float)mm.x;  tm[4*q+0] = (float)(tt.x & mm.x);
            m[4*q+1] = (float)mm.y;  tm[4*q+1] = (float)(tt.y & mm.y);
            m[4*q+2] = (float)mm.z;  tm[4*q+2] = (float)(tt.z & mm.z);
            m[4*q+3] = (float)mm.w;  tm[4*q+3] = (float)(tt.w & mm.w);
        }
#pragma unroll
        for (int q = 0; q < NELEM / 2; ++q) {
            const float4 pp = pv[q];                       // (p0,p1, p0,p1)
            const float pa = sigmoid_p(pp.x, pp.y);
            const float pb = sigmoid_p(pp.z, pp.w);
            pm [2*q+0] = pa * m[2*q+0];
            p2m[2*q+0] = pa * pa * m[2*q+0];
            pm [2*q+1] = pb * m[2*q+1];
            p2m[2*q+1] = pb * pb * m[2*q+1];
        }

        // initial window (elements 0..4)
        float sm  = m[0]  + m[1]  + m[2]  + m[3]  + m[4];
        float stm = tm[0] + tm[1] + tm[2] + tm[3] + tm[4];
        float spm = pm[0] + pm[1] + pm[2] + pm[3] + pm[4];
        float sp2 = p2m[0]+ p2m[1]+ p2m[2]+ p2m[3]+ p2m[4];

#pragma unroll
        for (int w = 0; w < NW; ++w) {
            // st2m == stm since t in {0,1}
            const float denom = fmaxf(sm, 1.0f);
            const float inv   = 1.0f / denom;
            const float pmean = spm * inv;
            const float tmean = stm * inv;
            const float pvar  = (sp2 - 2.0f * pmean * spm + pmean * pmean * sm) * inv;
            const float tvar  = (stm - 2.0f * tmean * stm + tmean * tmean * sm) * inv;
            const float d = pvar - tvar;
            accd2[w] += d * d;
            accms[w] += sm;
            if (w < NW - 1) {   // slide
                sm  += m[w + WIN]   - m[w];
                stm += tm[w + WIN]  - tm[w];
                spm += pm[w + WIN]  - pm[w];
                sp2 += p2m[w + WIN] - p2m[w];
            }
        }
    }

    // Contention-free partial stores. Tail run (1023) only owns j >= jfirst;
    // run 1022 owns j <= 16367 — disjoint, so plain stores are safe.
    float* pd = part_d2 + (size_t)blockIdx.y * WOUT;
    float* pm_out = part_ms + (size_t)blockIdx.y * WOUT;
    const int jfirst = run * NW;
#pragma unroll
    for (int w = 0; w < NW; ++w) {
        const int j = e0 + w;
        if (j >= jfirst) {
            pd[j]     = accd2[w];
            pm_out[j] = accms[w];
        }
    }
}

// Kernel 2: reduce partials over chunks per window -> mse*valid; block-reduce
// in double; atomic accumulate (64 blocks only); last block writes scalar.
__global__ void bcl_finalize(const float* __restrict__ part_d2,
                             const float* __restrict__ part_ms,
                             double* __restrict__ accum,   // [num, cnt]
                             unsigned int* __restrict__ ticket,
                             float* __restrict__ out,
                             int nchunks) {
    const int j = blockIdx.x * blockDim.x + threadIdx.x;
    double num = 0.0, cnt = 0.0;
    if (j < WOUT) {
        float d2 = 0.f, ms = 0.f;
        for (int c = 0; c < nchunks; ++c) {
            d2 += part_d2[(size_t)c * WOUT + j];
            ms += part_ms[(size_t)c * WOUT + j];
        }
        if (ms > 0.f) {
            num = (double)d2 * (1.0 / (double)BATCH);
            cnt = 1.0;
        }
    }
    for (int off = 32; off > 0; off >>= 1) {
        num += __shfl_down(num, off, 64);
        cnt += __shfl_down(cnt, off, 64);
    }
    __shared__ double s_num[4], s_cnt[4];
    const int lane = threadIdx.x & 63, wave = threadIdx.x >> 6;
    if (lane == 0) { s_num[wave] = num; s_cnt[wave] = cnt; }
    __syncthreads();
    if (threadIdx.x == 0) {
        double n = 0.0, c = 0.0;
        const int nw = (int)(blockDim.x >> 6);
        for (int wv = 0; wv < nw; ++wv) { n += s_num[wv]; c += s_cnt[wv]; }
        atomicAdd(&accum[0], n);
        atomicAdd(&accum[1], c);
        __threadfence();
        const unsigned int t = atomicAdd(ticket, 1u);
        if (t == gridDim.x - 1) {
            out[0] = (float)(accum[0] / fmax(accum[1], 1.0));
        }
    }
}

extern "C" void kernel_launch(void* const* d_in, const int* in_sizes, int n_in,
                              void* d_out, int out_size, void* d_ws, size_t ws_size,
                              hipStream_t stream) {
    const float* pred = (const float*)d_in[0];
    const int*   tgt  = (const int*)d_in[1];
    const int*   msk  = (const int*)d_in[2];
    float* out = (float*)d_out;

    // Workspace layout: [accum(2 dbl) | ticket | pad to 64 | part_d2 | part_ms]
    double* accum = (double*)d_ws;
    unsigned int* ticket = (unsigned int*)(accum + 2);
    float* parts = (float*)((char*)d_ws + 64);

    // Largest chunk count whose partials fit in ws (prefer 128 -> 512 blocks).
    int nchunks = 128;
    while (nchunks > 1) {
        size_t need = 64 + (size_t)nchunks * WOUT * 2 * sizeof(float);
        if (need <= ws_size) break;
        nchunks >>= 1;
    }
    const int bper = BATCH / nchunks;

    float* part_d2 = parts;
    float* part_ms = parts + (size_t)nchunks * WOUT;

    // Zero only accum+ticket (24 B); partials are fully overwritten.
    hipMemsetAsync(d_ws, 0, 64, stream);

    dim3 g1(RUNS / TPB, nchunks);   // (4, nchunks)
    bcl_main_kernel<<<g1, TPB, 0, stream>>>(pred, tgt, msk, part_d2, part_ms, bper);

    const int FBLKS = (WOUT + TPB - 1) / TPB;  // 64
    bcl_finalize<<<FBLKS, TPB, 0, stream>>>(part_d2, part_ms, accum, ticket, out, nchunks);
}

// Round 5
// 201.016 us; speedup vs baseline: 1.9856x; 1.1648x over previous
//
#include <hip/hip_runtime.h>
#include <math.h>

// Problem constants (from reference setup_inputs)
#define BATCH 512
#define LEN   16384
#define WIN   5
#define WOUT  (LEN - WIN + 1)   // 16380
#define NW    16                 // windows per run (register sliding window)
#define RUNS  ((WOUT + NW - 1) / NW)   // 1024 runs per row
#define NELEM (NW + WIN - 1)     // 20 elements loaded per (run, batch)
#define TPB   256
#define RPB   (TPB / 4)          // 64 runs per block; 4 batch-lanes per run

__device__ __forceinline__ float sigmoid_p(float p0, float p1) {
    // softmax over 2 classes, class 1
    return 1.0f / (1.0f + __expf(p0 - p1));
}

// Kernel 1: block = 64 runs x 4 batch-lanes. Each thread processes bseq
// batches for its run (bseq=1 at nchunks=128 -> 2048 blocks, full occupancy
// and max memory-level parallelism — round 4 died latency-bound at 512
// blocks). The 4 batch-lanes (adjacent wave lanes) butterfly-reduce via
// shfl_xor, then each lane writes 4 windows as ONE unit-stride float4
// (round 4's per-w scalar scatter caused 4x write amplification).
__global__ void bcl_main_kernel(const float* __restrict__ pred,
                                const int*   __restrict__ tgt,
                                const int*   __restrict__ msk,
                                float* __restrict__ part_d2,
                                float* __restrict__ part_ms,
                                int bseq) {
    const int x   = threadIdx.x >> 2;              // run within block, 0..63
    const int y   = threadIdx.x & 3;               // batch lane, 0..3
    const int run = blockIdx.x * RPB + x;          // 0..RUNS-1 (grid exact)
    const int e0  = min(run * NW, LEN - NELEM);    // clamp tail (run 1023)
    const int b0  = (blockIdx.y * 4 + y) * bseq;

    float accd2[NW], accms[NW];
#pragma unroll
    for (int w = 0; w < NW; ++w) { accd2[w] = 0.f; accms[w] = 0.f; }

    for (int b = b0; b < b0 + bseq; ++b) {
        const size_t rowoff = (size_t)b * LEN + e0;
        const int4*   mv = (const int4*)(msk + rowoff);
        const int4*   tv = (const int4*)(tgt + rowoff);
        const float4* pv = (const float4*)(pred + rowoff * 2);

        float m[NELEM], tm[NELEM], pm[NELEM], p2m[NELEM];
#pragma unroll
        for (int q = 0; q < NELEM / 4; ++q) {
            const int4 mm = mv[q];
            const int4 tt = tv[q];
            m[4*q+0] = (float)mm.x;  tm[4*q+0] = (float)(tt.x & mm.x);
            m[4*q+1] = (float)mm.y;  tm[4*q+1] = (float)(tt.y & mm.y);
            m[4*q+2] = (float)mm.z;  tm[4*q+2] = (float)(tt.z & mm.z);
            m[4*q+3] = (float)mm.w;  tm[4*q+3] = (float)(tt.w & mm.w);
        }
#pragma unroll
        for (int q = 0; q < NELEM / 2; ++q) {
            const float4 pp = pv[q];               // (p0,p1, p0,p1)
            const float pa = sigmoid_p(pp.x, pp.y);
            const float pb = sigmoid_p(pp.z, pp.w);
            pm [2*q+0] = pa * m[2*q+0];
            p2m[2*q+0] = pa * pa * m[2*q+0];
            pm [2*q+1] = pb * m[2*q+1];
            p2m[2*q+1] = pb * pb * m[2*q+1];
        }

        // initial window (elements 0..4)
        float sm  = m[0]  + m[1]  + m[2]  + m[3]  + m[4];
        float stm = tm[0] + tm[1] + tm[2] + tm[3] + tm[4];
        float spm = pm[0] + pm[1] + pm[2] + pm[3] + pm[4];
        float sp2 = p2m[0]+ p2m[1]+ p2m[2]+ p2m[3]+ p2m[4];

#pragma unroll
        for (int w = 0; w < NW; ++w) {
            // st2m == stm since t in {0,1}
            const float denom = fmaxf(sm, 1.0f);
            const float inv   = 1.0f / denom;
            const float pmean = spm * inv;
            const float tmean = stm * inv;
            const float pvar  = (sp2 - 2.0f * pmean * spm + pmean * pmean * sm) * inv;
            const float tvar  = (stm - 2.0f * tmean * stm + tmean * tmean * sm) * inv;
            const float d = pvar - tvar;
            accd2[w] += d * d;
            accms[w] += sm;
            if (w < NW - 1) {   // slide
                sm  += m[w + WIN]   - m[w];
                stm += tm[w + WIN]  - tm[w];
                spm += pm[w + WIN]  - pm[w];
                sp2 += p2m[w + WIN] - p2m[w];
            }
        }
    }

    // Butterfly-reduce the 4 batch-lanes of this run (lanes differ in bits 0-1).
#pragma unroll
    for (int w = 0; w < NW; ++w) {
        accd2[w] += __shfl_xor(accd2[w], 1);
        accd2[w] += __shfl_xor(accd2[w], 2);
        accms[w] += __shfl_xor(accms[w], 1);
        accms[w] += __shfl_xor(accms[w], 2);
    }

    // Lane y owns windows e0 + y*4 .. +3. Skip the tail run's duplicated
    // leading windows (they belong to run 1022; both compute identical data,
    // and the predicate makes ownership disjoint anyway).
    const int jbase = e0 + y * 4;
    if (jbase >= run * NW) {
        float* pd = part_d2 + (size_t)blockIdx.y * WOUT + jbase;
        float* pq = part_ms + (size_t)blockIdx.y * WOUT + jbase;
        *(float4*)pd = make_float4(accd2[y*4+0], accd2[y*4+1], accd2[y*4+2], accd2[y*4+3]);
        *(float4*)pq = make_float4(accms[y*4+0], accms[y*4+1], accms[y*4+2], accms[y*4+3]);
    }
}

// Kernel 2: reduce partials over chunks per window -> mse*valid; block-reduce
// in double; atomic accumulate (64 blocks only); last block writes scalar.
__global__ void bcl_finalize(const float* __restrict__ part_d2,
                             const float* __restrict__ part_ms,
                             double* __restrict__ accum,   // [num, cnt]
                             unsigned int* __restrict__ ticket,
                             float* __restrict__ out,
                             int nchunks) {
    const int j = blockIdx.x * blockDim.x + threadIdx.x;
    double num = 0.0, cnt = 0.0;
    if (j < WOUT) {
        float d2a = 0.f, d2b = 0.f, msa = 0.f, msb = 0.f;
        int c = 0;
        for (; c + 1 < nchunks; c += 2) {
            d2a += part_d2[(size_t)c * WOUT + j];
            d2b += part_d2[(size_t)(c + 1) * WOUT + j];
            msa += part_ms[(size_t)c * WOUT + j];
            msb += part_ms[(size_t)(c + 1) * WOUT + j];
        }
        for (; c < nchunks; ++c) {
            d2a += part_d2[(size_t)c * WOUT + j];
            msa += part_ms[(size_t)c * WOUT + j];
        }
        const float d2 = d2a + d2b;
        const float ms = msa + msb;
        if (ms > 0.f) {
            num = (double)d2 * (1.0 / (double)BATCH);
            cnt = 1.0;
        }
    }
    for (int off = 32; off > 0; off >>= 1) {
        num += __shfl_down(num, off, 64);
        cnt += __shfl_down(cnt, off, 64);
    }
    __shared__ double s_num[4], s_cnt[4];
    const int lane = threadIdx.x & 63, wave = threadIdx.x >> 6;
    if (lane == 0) { s_num[wave] = num; s_cnt[wave] = cnt; }
    __syncthreads();
    if (threadIdx.x == 0) {
        double n = 0.0, c = 0.0;
        const int nw = (int)(blockDim.x >> 6);
        for (int wv = 0; wv < nw; ++wv) { n += s_num[wv]; c += s_cnt[wv]; }
        atomicAdd(&accum[0], n);
        atomicAdd(&accum[1], c);
        __threadfence();
        const unsigned int t = atomicAdd(ticket, 1u);
        if (t == gridDim.x - 1) {
            out[0] = (float)(accum[0] / fmax(accum[1], 1.0));
        }
    }
}

extern "C" void kernel_launch(void* const* d_in, const int* in_sizes, int n_in,
                              void* d_out, int out_size, void* d_ws, size_t ws_size,
                              hipStream_t stream) {
    const float* pred = (const float*)d_in[0];
    const int*   tgt  = (const int*)d_in[1];
    const int*   msk  = (const int*)d_in[2];
    float* out = (float*)d_out;

    // Workspace layout: [accum(2 dbl) | ticket | pad to 64 | part_d2 | part_ms]
    double* accum = (double*)d_ws;
    unsigned int* ticket = (unsigned int*)(accum + 2);
    float* parts = (float*)((char*)d_ws + 64);

    // Largest chunk count whose partials fit in ws (prefer 128: bseq=1,
    // 2048 blocks, full occupancy). Each chunk spans 4 batch-lanes * bseq.
    int nchunks = 128;
    while (nchunks > 1) {
        size_t need = 64 + (size_t)nchunks * WOUT * 2 * sizeof(float);
        if (need <= ws_size) break;
        nchunks >>= 1;
    }
    const int bseq = BATCH / (nchunks * 4);

    float* part_d2 = parts;
    float* part_ms = parts + (size_t)nchunks * WOUT;

    // Zero only accum+ticket (24 B); partials are fully overwritten.
    hipMemsetAsync(d_ws, 0, 64, stream);

    dim3 g1(RUNS / RPB, nchunks);   // (16, 128) = 2048 blocks
    bcl_main_kernel<<<g1, TPB, 0, stream>>>(pred, tgt, msk, part_d2, part_ms, bseq);

    const int FBLKS = (WOUT + TPB - 1) / TPB;  // 64
    bcl_finalize<<<FBLKS, TPB, 0, stream>>>(part_d2, part_ms, accum, ticket, out, nchunks);
}

// Round 6
// 174.420 us; speedup vs baseline: 2.2883x; 1.1525x over previous
//
#include <hip/hip_runtime.h>
#include <math.h>

// Problem constants (from reference setup_inputs)
#define BATCH 512
#define LEN   16384
#define WIN   5
#define WOUT  (LEN - WIN + 1)   // 16380
#define NW    16                 // windows per run (register sliding window)
#define RUNS  ((WOUT + NW - 1) / NW)   // 1024 runs per row
#define NELEM (NW + WIN - 1)     // 20 elements loaded per (run, batch)
#define TPB   256
#define RPB   (TPB / 4)          // 64 runs per block; 4 batch-lanes per run

__device__ __forceinline__ float sigmoid_p(float p0, float p1) {
    // softmax over 2 classes, class 1
    return 1.0f / (1.0f + __expf(p0 - p1));
}

// Kernel 1: block = 64 runs x 4 batch-lanes, grid (16, 128) = 2048 blocks.
// Round 5 spilled ~73 MB to scratch (112+ live regs vs VGPR_Count=64).
// Fixes: (a) m,t bit-packed into 2 ints — window sums via __popc (exact);
// (b) per-window EARLY butterfly so each lane keeps only its 4 owned
// windows (8 acc regs instead of 32); (c) launch_bounds(256,4) = 128 VGPR
// cap, no spill. Only float arrays left: pm[20], p2m[20].
__global__ __launch_bounds__(TPB, 4)
void bcl_main_kernel(const float* __restrict__ pred,
                     const int*   __restrict__ tgt,
                     const int*   __restrict__ msk,
                     float* __restrict__ part_d2,
                     float* __restrict__ part_ms,
                     int bseq) {
    const int x   = threadIdx.x >> 2;              // run within block, 0..63
    const int y   = threadIdx.x & 3;               // batch lane, 0..3
    const int run = blockIdx.x * RPB + x;          // 0..RUNS-1 (grid exact)
    const int e0  = min(run * NW, LEN - NELEM);    // clamp tail (run 1023)
    const int b0  = (blockIdx.y * 4 + y) * bseq;

    float rd2[4], rms[4];                          // this lane's 4 owned windows
#pragma unroll
    for (int w = 0; w < 4; ++w) { rd2[w] = 0.f; rms[w] = 0.f; }

    for (int b = b0; b < b0 + bseq; ++b) {
        const size_t rowoff = (size_t)b * LEN + e0;
        const int4*   mv = (const int4*)(msk + rowoff);
        const int4*   tv = (const int4*)(tgt + rowoff);
        const float4* pv = (const float4*)(pred + rowoff * 2);

        // ---- bit-pack mask & target&mask (elements are 0/1 ints) ----
        unsigned mb = 0, tb = 0;
#pragma unroll
        for (int q = 0; q < NELEM / 4; ++q) {
            const int4 mm = mv[q];
            const int4 tt = tv[q];
            mb |= (unsigned)(mm.x << (4*q)) | (unsigned)(mm.y << (4*q+1))
                | (unsigned)(mm.z << (4*q+2)) | (unsigned)(mm.w << (4*q+3));
            tb |= (unsigned)((tt.x & mm.x) << (4*q)) | (unsigned)((tt.y & mm.y) << (4*q+1))
                | (unsigned)((tt.z & mm.z) << (4*q+2)) | (unsigned)((tt.w & mm.w) << (4*q+3));
        }

        // ---- probabilities (1 sigmoid per element), masked p and p^2 ----
        float pm[NELEM], p2m[NELEM];
#pragma unroll
        for (int q = 0; q < NELEM / 2; ++q) {
            const float4 pp = pv[q];               // elements 2q, 2q+1
            const float pa = sigmoid_p(pp.x, pp.y);
            const float pb = sigmoid_p(pp.z, pp.w);
            const float ma = (float)((mb >> (2*q)) & 1u);
            const float mbf = (float)((mb >> (2*q+1)) & 1u);
            pm [2*q+0] = pa * ma;   p2m[2*q+0] = pa * pa * ma;
            pm [2*q+1] = pb * mbf;  p2m[2*q+1] = pb * pb * mbf;
        }

        // ---- sliding window sums ----
        float spm = pm[0] + pm[1] + pm[2] + pm[3] + pm[4];
        float sp2 = p2m[0] + p2m[1] + p2m[2] + p2m[3] + p2m[4];

#pragma unroll
        for (int w = 0; w < NW; ++w) {
            const float msum = (float)__popc((mb >> w) & 31u);  // exact
            const float stm  = (float)__popc((tb >> w) & 31u);  // exact
            // st2m == stm since t in {0,1}
            const float denom = fmaxf(msum, 1.0f);
            const float inv   = 1.0f / denom;
            const float pmean = spm * inv;
            const float tmean = stm * inv;
            const float pvar  = (sp2 - 2.0f * pmean * spm + pmean * pmean * msum) * inv;
            const float tvar  = (stm - 2.0f * tmean * stm + tmean * tmean * msum) * inv;
            const float d = pvar - tvar;

            // early butterfly over the 4 batch-lanes (lane bits 0-1)
            float d2 = d * d, ms = msum;
            d2 += __shfl_xor(d2, 1);  d2 += __shfl_xor(d2, 2);
            ms += __shfl_xor(ms, 1);  ms += __shfl_xor(ms, 2);
            if ((w >> 2) == y) { rd2[w & 3] += d2; rms[w & 3] += ms; }

            if (w < NW - 1) {   // slide float sums
                spm += pm[w + WIN] - pm[w];
                sp2 += p2m[w + WIN] - p2m[w];
            }
        }
    }

    // Lane y owns windows e0 + y*4 .. +3 as one unit-stride float4.
    // Tail run (1023): windows below run*NW belong to run 1022 — skip.
    const int jbase = e0 + y * 4;
    if (jbase >= run * NW) {
        float* pd = part_d2 + (size_t)blockIdx.y * WOUT + jbase;
        float* pq = part_ms + (size_t)blockIdx.y * WOUT + jbase;
        *(float4*)pd = make_float4(rd2[0], rd2[1], rd2[2], rd2[3]);
        *(float4*)pq = make_float4(rms[0], rms[1], rms[2], rms[3]);
    }
}

// Kernel 2: reduce partials over chunks per window -> mse*valid; block-reduce
// in double; atomic accumulate (64 blocks only); last block writes scalar.
__global__ void bcl_finalize(const float* __restrict__ part_d2,
                             const float* __restrict__ part_ms,
                             double* __restrict__ accum,   // [num, cnt]
                             unsigned int* __restrict__ ticket,
                             float* __restrict__ out,
                             int nchunks) {
    const int j = blockIdx.x * blockDim.x + threadIdx.x;
    double num = 0.0, cnt = 0.0;
    if (j < WOUT) {
        float d2a = 0.f, d2b = 0.f, msa = 0.f, msb = 0.f;
        int c = 0;
        for (; c + 1 < nchunks; c += 2) {
            d2a += part_d2[(size_t)c * WOUT + j];
            d2b += part_d2[(size_t)(c + 1) * WOUT + j];
            msa += part_ms[(size_t)c * WOUT + j];
            msb += part_ms[(size_t)(c + 1) * WOUT + j];
        }
        for (; c < nchunks; ++c) {
            d2a += part_d2[(size_t)c * WOUT + j];
            msa += part_ms[(size_t)c * WOUT + j];
        }
        const float d2 = d2a + d2b;
        const float ms = msa + msb;
        if (ms > 0.f) {
            num = (double)d2 * (1.0 / (double)BATCH);
            cnt = 1.0;
        }
    }
    for (int off = 32; off > 0; off >>= 1) {
        num += __shfl_down(num, off, 64);
        cnt += __shfl_down(cnt, off, 64);
    }
    __shared__ double s_num[4], s_cnt[4];
    const int lane = threadIdx.x & 63, wave = threadIdx.x >> 6;
    if (lane == 0) { s_num[wave] = num; s_cnt[wave] = cnt; }
    __syncthreads();
    if (threadIdx.x == 0) {
        double n = 0.0, c = 0.0;
        const int nw = (int)(blockDim.x >> 6);
        for (int wv = 0; wv < nw; ++wv) { n += s_num[wv]; c += s_cnt[wv]; }
        atomicAdd(&accum[0], n);
        atomicAdd(&accum[1], c);
        __threadfence();
        const unsigned int t = atomicAdd(ticket, 1u);
        if (t == gridDim.x - 1) {
            out[0] = (float)(accum[0] / fmax(accum[1], 1.0));
        }
    }
}

extern "C" void kernel_launch(void* const* d_in, const int* in_sizes, int n_in,
                              void* d_out, int out_size, void* d_ws, size_t ws_size,
                              hipStream_t stream) {
    const float* pred = (const float*)d_in[0];
    const int*   tgt  = (const int*)d_in[1];
    const int*   msk  = (const int*)d_in[2];
    float* out = (float*)d_out;

    // Workspace layout: [accum(2 dbl) | ticket | pad to 64 | part_d2 | part_ms]
    double* accum = (double*)d_ws;
    unsigned int* ticket = (unsigned int*)(accum + 2);
    float* parts = (float*)((char*)d_ws + 64);

    // Largest chunk count whose partials fit in ws (prefer 128: bseq=1,
    // 2048 blocks). Each chunk spans 4 batch-lanes * bseq.
    int nchunks = 128;
    while (nchunks > 1) {
        size_t need = 64 + (size_t)nchunks * WOUT * 2 * sizeof(float);
        if (need <= ws_size) break;
        nchunks >>= 1;
    }
    const int bseq = BATCH / (nchunks * 4);

    float* part_d2 = parts;
    float* part_ms = parts + (size_t)nchunks * WOUT;

    // Zero only accum+ticket (24 B); partials are fully overwritten.
    hipMemsetAsync(d_ws, 0, 64, stream);

    dim3 g1(RUNS / RPB, nchunks);   // (16, 128) = 2048 blocks
    bcl_main_kernel<<<g1, TPB, 0, stream>>>(pred, tgt, msk, part_d2, part_ms, bseq);

    const int FBLKS = (WOUT + TPB - 1) / TPB;  // 64
    bcl_finalize<<<FBLKS, TPB, 0, stream>>>(part_d2, part_ms, accum, ticket, out, nchunks);
}

// Round 7
// 173.984 us; speedup vs baseline: 2.2941x; 1.0025x over previous
//
#include <hip/hip_runtime.h>
#include <math.h>

// Problem constants (from reference setup_inputs)
#define BATCH 512
#define LEN   16384
#define WIN   5
#define WOUT  (LEN - WIN + 1)   // 16380
#define NW    16                 // windows per run (register sliding window)
#define RUNS  ((WOUT + NW - 1) / NW)   // 1024 runs per row
#define NELEM (NW + WIN - 1)     // 20 elements loaded per (run, batch)
#define TPB   256
#define RPB   (TPB / 4)          // 64 runs per block; 4 batch-lanes per run
#define NCHUNK 128               // batch chunks (bseq = 1)

__device__ __forceinline__ float sigmoid_p(float p0, float p1) {
    // softmax over 2 classes, class 1
    return 1.0f / (1.0f + __expf(p0 - p1));
}

// Kernel 1: block = 64 runs x 4 batch-lanes, grid (16, 128) = 2048 blocks,
// one batch per thread. Round 6 was latency-bound at VGPR_Count=64: one
// batch's raw loads need 80 regs, so the compiler serialized the 20 loads.
// launch_bounds(256,2) lets the allocator keep all 20 outstanding (MLP)
// while still allowing 16 waves/CU at <=128 VGPR.
__global__ __launch_bounds__(TPB, 2)
void bcl_main_kernel(const float* __restrict__ pred,
                     const int*   __restrict__ tgt,
                     const int*   __restrict__ msk,
                     float* __restrict__ part_d2,
                     float* __restrict__ part_ms) {
    const int x   = threadIdx.x >> 2;              // run within block, 0..63
    const int y   = threadIdx.x & 3;               // batch lane, 0..3
    const int run = blockIdx.x * RPB + x;          // 0..RUNS-1 (grid exact)
    const int e0  = min(run * NW, LEN - NELEM);    // clamp tail (run 1023)
    const int b   = blockIdx.y * 4 + y;            // this thread's batch row

    const size_t rowoff = (size_t)b * LEN + e0;
    const int4*   mv = (const int4*)(msk + rowoff);
    const int4*   tv = (const int4*)(tgt + rowoff);
    const float4* pv = (const float4*)(pred + rowoff * 2);

    // ---- issue all 20 loads (compiler hoists; needs ~80 regs live) ----
    int4 mr[NELEM / 4], tr[NELEM / 4];
    float4 pr[NELEM / 2];
#pragma unroll
    for (int q = 0; q < NELEM / 4; ++q) { mr[q] = mv[q]; tr[q] = tv[q]; }
#pragma unroll
    for (int q = 0; q < NELEM / 2; ++q) { pr[q] = pv[q]; }

    // ---- bit-pack mask & target&mask (elements are 0/1 ints) ----
    unsigned mb = 0, tb = 0;
#pragma unroll
    for (int q = 0; q < NELEM / 4; ++q) {
        const int4 mm = mr[q];
        const int4 tt = tr[q];
        mb |= (unsigned)(mm.x << (4*q)) | (unsigned)(mm.y << (4*q+1))
            | (unsigned)(mm.z << (4*q+2)) | (unsigned)(mm.w << (4*q+3));
        tb |= (unsigned)((tt.x & mm.x) << (4*q)) | (unsigned)((tt.y & mm.y) << (4*q+1))
            | (unsigned)((tt.z & mm.z) << (4*q+2)) | (unsigned)((tt.w & mm.w) << (4*q+3));
    }

    // ---- probabilities (1 sigmoid per element), masked p and p^2 ----
    float pm[NELEM], p2m[NELEM];
#pragma unroll
    for (int q = 0; q < NELEM / 2; ++q) {
        const float4 pp = pr[q];               // elements 2q, 2q+1
        const float pa = sigmoid_p(pp.x, pp.y);
        const float pb = sigmoid_p(pp.z, pp.w);
        const float ma  = (float)((mb >> (2*q)) & 1u);
        const float mbf = (float)((mb >> (2*q+1)) & 1u);
        pm [2*q+0] = pa * ma;   p2m[2*q+0] = pa * pa * ma;
        pm [2*q+1] = pb * mbf;  p2m[2*q+1] = pb * pb * mbf;
    }

    // ---- sliding window sums + per-window butterfly over 4 batch-lanes ----
    float rd2[4], rms[4];                      // this lane's 4 owned windows
#pragma unroll
    for (int w = 0; w < 4; ++w) { rd2[w] = 0.f; rms[w] = 0.f; }

    float spm = pm[0] + pm[1] + pm[2] + pm[3] + pm[4];
    float sp2 = p2m[0] + p2m[1] + p2m[2] + p2m[3] + p2m[4];

#pragma unroll
    for (int w = 0; w < NW; ++w) {
        const float msum = (float)__popc((mb >> w) & 31u);  // exact
        const float stm  = (float)__popc((tb >> w) & 31u);  // exact
        // st2m == stm since t in {0,1}
        const float denom = fmaxf(msum, 1.0f);
        const float inv   = 1.0f / denom;
        const float pmean = spm * inv;
        const float tmean = stm * inv;
        const float pvar  = (sp2 - 2.0f * pmean * spm + pmean * pmean * msum) * inv;
        const float tvar  = (stm - 2.0f * tmean * stm + tmean * tmean * msum) * inv;
        const float d = pvar - tvar;

        // butterfly over the 4 batch-lanes (lane bits 0-1)
        float d2 = d * d, ms = msum;
        d2 += __shfl_xor(d2, 1);  d2 += __shfl_xor(d2, 2);
        ms += __shfl_xor(ms, 1);  ms += __shfl_xor(ms, 2);
        if ((w >> 2) == y) { rd2[w & 3] = d2; rms[w & 3] = ms; }

        if (w < NW - 1) {   // slide float sums
            spm += pm[w + WIN] - pm[w];
            sp2 += p2m[w + WIN] - p2m[w];
        }
    }

    // Lane y owns windows e0 + y*4 .. +3 as one unit-stride float4.
    // Tail run (1023): windows below run*NW belong to run 1022 — skip.
    const int jbase = e0 + y * 4;
    if (jbase >= run * NW) {
        float* pd = part_d2 + (size_t)blockIdx.y * WOUT + jbase;
        float* pq = part_ms + (size_t)blockIdx.y * WOUT + jbase;
        *(float4*)pd = make_float4(rd2[0], rd2[1], rd2[2], rd2[3]);
        *(float4*)pq = make_float4(rms[0], rms[1], rms[2], rms[3]);
    }
}

// Kernel 2: reduce partials over chunks per window -> mse*valid.
// 256 single-wave blocks so all CUs participate in the 16.8 MB read;
// wave-reduce in double, one atomic pair per block, ticketed finalize.
#define FTPB 64
#define FBLKS 256
#define JPB  ((WOUT + FBLKS - 1) / FBLKS)   // 64 windows per block

__global__ __launch_bounds__(FTPB, 1)
void bcl_finalize(const float* __restrict__ part_d2,
                  const float* __restrict__ part_ms,
                  double* __restrict__ accum,   // [num, cnt]
                  unsigned int* __restrict__ ticket,
                  float* __restrict__ out) {
    const int j = blockIdx.x * JPB + threadIdx.x;
    double num = 0.0, cnt = 0.0;
    if (j < WOUT && threadIdx.x < JPB) {
        float d2a = 0.f, d2b = 0.f, msa = 0.f, msb = 0.f;
        for (int c = 0; c < NCHUNK; c += 2) {
            d2a += part_d2[(size_t)c * WOUT + j];
            d2b += part_d2[(size_t)(c + 1) * WOUT + j];
            msa += part_ms[(size_t)c * WOUT + j];
            msb += part_ms[(size_t)(c + 1) * WOUT + j];
        }
        const float d2 = d2a + d2b;
        const float ms = msa + msb;
        if (ms > 0.f) {
            num = (double)d2 * (1.0 / (double)BATCH);
            cnt = 1.0;
        }
    }
    for (int off = 32; off > 0; off >>= 1) {
        num += __shfl_down(num, off, 64);
        cnt += __shfl_down(cnt, off, 64);
    }
    if (threadIdx.x == 0) {
        atomicAdd(&accum[0], num);
        atomicAdd(&accum[1], cnt);
        __threadfence();
        const unsigned int t = atomicAdd(ticket, 1u);
        if (t == gridDim.x - 1) {
            out[0] = (float)(accum[0] / fmax(accum[1], 1.0));
        }
    }
}

extern "C" void kernel_launch(void* const* d_in, const int* in_sizes, int n_in,
                              void* d_out, int out_size, void* d_ws, size_t ws_size,
                              hipStream_t stream) {
    const float* pred = (const float*)d_in[0];
    const int*   tgt  = (const int*)d_in[1];
    const int*   msk  = (const int*)d_in[2];
    float* out = (float*)d_out;

    // Workspace layout: [accum(2 dbl) | ticket | pad to 64 | part_d2 | part_ms]
    double* accum = (double*)d_ws;
    unsigned int* ticket = (unsigned int*)(accum + 2);
    float* part_d2 = (float*)((char*)d_ws + 64);
    float* part_ms = part_d2 + (size_t)NCHUNK * WOUT;

    // Zero only accum+ticket; partials are fully overwritten.
    hipMemsetAsync(d_ws, 0, 64, stream);

    dim3 g1(RUNS / RPB, NCHUNK);   // (16, 128) = 2048 blocks
    bcl_main_kernel<<<g1, TPB, 0, stream>>>(pred, tgt, msk, part_d2, part_ms);

    bcl_finalize<<<FBLKS, FTPB, 0, stream>>>(part_d2, part_ms, accum, ticket, out);
}